// Round 12
// baseline (25.851 us; speedup 1.0000x reference)
//
#include <hip/hip_runtime.h>

// FFT convolution via N = 2^18 = 64 x 4096 Cooley-Tukey, 3 dispatches (minimum for
// the four-step dependency structure: col-pass | row-local middle | col-pass).
//   n = 4096*n1 + n2, k = k1 + 64*k2.
// ka : distributed 64-pt column FFT over n1 (+ W_N^{-n2 k1})   -> A1[seq][k1][n2]
//      t = tid>>6 wave-uniform, c = tid&63 -> all global I/O coalesced (R11 win).
// kb : per (z,k1) row: fwd 4096-FFT of rir row (spectrum in 16 VGPRs, recomputed
//      per z -- cheaper than any cross-block handshake, R6/R9/R10 lessons), fwd
//      4096-FFT of z row, pointwise*1/N, inverse FFT, +W_N^{+n2 k1} -> D[z][k1][n2]
//      Both global loads issued before the first FFT (latency hidden under it).
// kc : distributed 64-pt inverse column FFT over k1, unpack    -> out

#define NTOT 262144
#define TLEN 131072
#define PI2_N     2.3968449808418217e-5f   /* 2*pi / 262144 */
#define PI2_32768 1.9174759848570515e-4f   /* 2*pi / 32768  */
#define PI2_4096  1.5339807878856412e-3f   /* 2*pi / 4096   */
#define PI2_512   1.2271846303085129e-2f   /* 2*pi / 512    */
#define PI2_64    9.8174770424681039e-2f   /* 2*pi / 64     */
#define LB(i) ((i) + ((i) >> 3))           /* LDS pad for row-FFT buffers */

__device__ __forceinline__ float2 cadd(float2 a, float2 b) { return make_float2(a.x + b.x, a.y + b.y); }
__device__ __forceinline__ float2 csub(float2 a, float2 b) { return make_float2(a.x - b.x, a.y - b.y); }
__device__ __forceinline__ float2 cmul(float2 a, float2 b) {
    return make_float2(a.x * b.x - a.y * b.y, a.x * b.y + a.y * b.x);
}
__device__ __forceinline__ float2 cmulc(float2 a, float2 b) {   // a * conj(b)
    return make_float2(a.x * b.x + a.y * b.y, a.y * b.x - a.x * b.y);
}
__device__ __forceinline__ float2 cexp_(float ang) {
    float s, c;
    __sincosf(ang, &s, &c);
    return make_float2(c, s);
}

template<int SIGN>
__device__ __forceinline__ void dft8(float2 x[8]) {
    const float R2 = 0.70710678118654752f;
    float2 t0 = cadd(x[0], x[4]), t1 = csub(x[0], x[4]);
    float2 t2 = cadd(x[2], x[6]), t3 = csub(x[2], x[6]);
    float2 u0 = cadd(x[1], x[5]), u1 = csub(x[1], x[5]);
    float2 u2 = cadd(x[3], x[7]), u3 = csub(x[3], x[7]);
    float2 it3 = (SIGN > 0) ? make_float2(-t3.y, t3.x) : make_float2(t3.y, -t3.x);
    float2 iu3 = (SIGN > 0) ? make_float2(-u3.y, u3.x) : make_float2(u3.y, -u3.x);
    float2 E0 = cadd(t0, t2), E2 = csub(t0, t2);
    float2 E1 = cadd(t1, it3), E3 = csub(t1, it3);
    float2 O0 = cadd(u0, u2), O2 = csub(u0, u2);
    float2 O1 = cadd(u1, iu3), O3 = csub(u1, iu3);
    float2 iO2 = (SIGN > 0) ? make_float2(-O2.y, O2.x) : make_float2(O2.y, -O2.x);
    float2 w1O1 = (SIGN > 0) ? make_float2(R2 * (O1.x - O1.y), R2 * (O1.y + O1.x))
                             : make_float2(R2 * (O1.x + O1.y), R2 * (O1.y - O1.x));
    float2 w3O3 = (SIGN > 0) ? make_float2(R2 * (-O3.x - O3.y), R2 * (O3.x - O3.y))
                             : make_float2(R2 * (O3.y - O3.x), R2 * (-O3.x - O3.y));
    x[0] = cadd(E0, O0);   x[4] = csub(E0, O0);
    x[1] = cadd(E1, w1O1); x[5] = csub(E1, w1O1);
    x[2] = cadd(E2, iO2);  x[6] = csub(E2, iO2);
    x[3] = cadd(E3, w3O3); x[7] = csub(E3, w3O3);
}

// dft8 with x[4..7] == 0 structurally (reads only x[0..3])
template<int SIGN>
__device__ __forceinline__ void dft8z(float2 x[8]) {
    const float R2 = 0.70710678118654752f;
    float2 x0 = x[0], x1 = x[1], x2 = x[2], x3 = x[3];
    float2 rx2 = (SIGN > 0) ? make_float2(-x2.y, x2.x) : make_float2(x2.y, -x2.x);
    float2 rx3 = (SIGN > 0) ? make_float2(-x3.y, x3.x) : make_float2(x3.y, -x3.x);
    float2 E0 = cadd(x0, x2), E2 = csub(x0, x2);
    float2 E1 = cadd(x0, rx2), E3 = csub(x0, rx2);
    float2 O0 = cadd(x1, x3), O2 = csub(x1, x3);
    float2 O1 = cadd(x1, rx3), O3 = csub(x1, rx3);
    float2 iO2 = (SIGN > 0) ? make_float2(-O2.y, O2.x) : make_float2(O2.y, -O2.x);
    float2 w1O1 = (SIGN > 0) ? make_float2(R2 * (O1.x - O1.y), R2 * (O1.y + O1.x))
                             : make_float2(R2 * (O1.x + O1.y), R2 * (O1.y - O1.x));
    float2 w3O3 = (SIGN > 0) ? make_float2(R2 * (-O3.x - O3.y), R2 * (O3.x - O3.y))
                             : make_float2(R2 * (O3.y - O3.x), R2 * (-O3.x - O3.y));
    x[0] = cadd(E0, O0);   x[4] = csub(E0, O0);
    x[1] = cadd(E1, w1O1); x[5] = csub(E1, w1O1);
    x[2] = cadd(E2, iO2);  x[6] = csub(E2, iO2);
    x[3] = cadd(E3, w3O3); x[7] = csub(E3, w3O3);
}

// twiddle by W4096^(base*i) from table (tab[j] = e^{-2pi i j/4096}); conj for inverse.
template<int SIGN>
__device__ __forceinline__ void twtab(float2 x[8], int base, const float2* __restrict__ tab) {
#pragma unroll
    for (int i = 1; i < 8; ++i) {
        float2 w = tab[base * i];
        x[i] = (SIGN < 0) ? cmul(x[i], w) : cmulc(x[i], w);
    }
}

// 4096-pt radix-8 Stockham FFT, t in [0,512), double-buffered LDS L0/L1.
// Leading __syncthreads makes back-to-back calls (kb) WAR-safe.
template<int SIGN>
__device__ void fft4096(float2 x[8], int t, float2* L0, float2* L1,
                        const float2* __restrict__ tab) {
    __syncthreads();
    dft8<SIGN>(x);
    twtab<SIGN>(x, t, tab);
#pragma unroll
    for (int i = 0; i < 8; ++i) L0[LB(8 * t + i)] = x[i];
    __syncthreads();
    {
        int q = t & 7, p = t >> 3;
#pragma unroll
        for (int i = 0; i < 8; ++i) x[i] = L0[LB(q + 8 * p + 512 * i)];
        dft8<SIGN>(x);
        twtab<SIGN>(x, 8 * p, tab);
#pragma unroll
        for (int i = 0; i < 8; ++i) L1[LB(q + 64 * p + 8 * i)] = x[i];
    }
    __syncthreads();
    {
        int q = t & 63, p = t >> 6;
#pragma unroll
        for (int i = 0; i < 8; ++i) x[i] = L1[LB(q + 64 * p + 512 * i)];
        dft8<SIGN>(x);
        twtab<SIGN>(x, 64 * p, tab);
#pragma unroll
        for (int i = 0; i < 8; ++i) L0[LB(q + 512 * p + 64 * i)] = x[i];
    }
    __syncthreads();
#pragma unroll
    for (int i = 0; i < 8; ++i) x[i] = L0[LB(t + 512 * i)];
    dft8<SIGN>(x);
}

// ka: 192 blocks x 512. Distributed 64-pt column FFT.
// t = tid>>6 (wave-uniform), c = tid&63 (lane-consecutive n2).
__global__ void __launch_bounds__(512) ka(const float* __restrict__ audio,
                                          const float* __restrict__ rir,
                                          float2* __restrict__ A1,
                                          float2* __restrict__ tab) {
    __shared__ float2 Lsh[64 * 64];       // [j][c], 32 KB, conflict-free
    const int bid = blockIdx.x;
    const int tid = threadIdx.x;
    const int t = tid >> 6;               // radix-8 slot (uniform per wave)
    const int c = tid & 63;               // column within block

    if (bid < 8)                          // fill W4096 table (read by kb/kc next)
        tab[bid * 512 + tid] = cexp_(-PI2_4096 * (float)(bid * 512 + tid));

    int seq = bid >> 6;
    int n2 = ((bid & 63) << 6) + c;
    float2 g[8];
    if (seq < 2) {
        const float* c0 = audio + (size_t)(2 * seq) * TLEN;
        const float* c1 = c0 + TLEN;
#pragma unroll
        for (int i = 0; i < 4; ++i) {
            int n = ((t + 8 * i) << 12) + n2;          // n1 = t+8i < 32 (nonzero half)
            g[i] = make_float2(c0[n], c1[n]);          // lanes: 64 consecutive floats
        }
    } else {
#pragma unroll
        for (int i = 0; i < 4; ++i) {
            int n = ((t + 8 * i) << 12) + n2;
            g[i] = make_float2(rir[TLEN - 1 - n], 0.f);
        }
    }
    dft8z<-1>(g);
#pragma unroll
    for (int i = 1; i < 8; ++i)
        g[i] = cmul(g[i], cexp_(-PI2_64 * (float)(t * i)));
#pragma unroll
    for (int i = 0; i < 8; ++i) Lsh[(t + 8 * i) * 64 + c] = g[i];   // phys x[t+8i]
    __syncthreads();
#pragma unroll
    for (int i = 0; i < 8; ++i) g[i] = Lsh[(8 * t + i) * 64 + c];   // phys x[8t+i]
    dft8<-1>(g);
    // W_N^{-n2*(8i+t)} = W_N^{-n2 t} * (W_N^{-8 n2})^i
    float2 w  = cexp_(-PI2_N * (float)(n2 * t));
    float2 st = cexp_(-PI2_32768 * (float)n2);
    float2* dst = A1 + ((size_t)seq << 18) + n2;
#pragma unroll
    for (int i = 0; i < 8; ++i) {
        dst[(size_t)(8 * i + t) << 12] = cmul(g[i], w);   // k1 = rev8(8t+i) = 8i+t
        w = cmul(w, st);                                  // lanes: 512B coalesced
    }
}

// kb: 128 blocks x 512. z = bid>>6, k1 = bid&63. Row-local middle:
// fwd FFT(rir row k1) -> regs; fwd FFT(z row); pointwise*1/N; inv FFT; twiddle; -> D.
__global__ void __launch_bounds__(512) kb(const float2* __restrict__ A1,
                                          float2* __restrict__ D,
                                          const float2* __restrict__ tab) {
    int k1 = blockIdx.x & 63;
    int t = threadIdx.x;
    __shared__ float2 L0[4608], L1[4608];

    const float2* sz = A1 + ((size_t)blockIdx.x << 12);            // z row = z*64+k1 = bid
    const float2* sr = A1 + ((size_t)(128 + k1) << 12);            // rir row
    float2 x[8], r8[8];
#pragma unroll
    for (int i = 0; i < 8; ++i) x[i] = sz[t + 512 * i];            // issue early:
#pragma unroll
    for (int i = 0; i < 8; ++i) r8[i] = sr[t + 512 * i];           // both rows in flight

    fft4096<-1>(r8, t, L0, L1, tab);     // rir spectrum -> 16 VGPRs (z loads hide here)
    fft4096<-1>(x, t, L0, L1, tab);      // z spectrum

    const float invN = 3.814697265625e-6f;  // 1/262144
#pragma unroll
    for (int i = 0; i < 8; ++i) {
        float2 y = cmul(x[i], r8[i]);
        x[i] = make_float2(y.x * invN, y.y * invN);
    }

    fft4096<1>(x, t, L0, L1, tab);

    // W_N^{+n2 k1}, n2 = t+512i: chain from W_N^{t k1}, step W_512^{k1}
    float2 w  = cexp_(PI2_N * (float)(t * k1));
    float2 st = cexp_(PI2_512 * (float)k1);
    float2* d = D + ((size_t)blockIdx.x << 12) + t;
#pragma unroll
    for (int i = 0; i < 8; ++i) {
        d[512 * i] = cmul(x[i], w);
        w = cmul(w, st);
    }
}

// kc: 128 blocks x 512. Distributed 64-pt inverse column FFT over k1 + unpack.
__global__ void __launch_bounds__(512) kc(const float2* __restrict__ D,
                                          float* __restrict__ out, int Lout,
                                          const float2* __restrict__ tab) {
    __shared__ float2 Lsh[64 * 64];       // [j][c]
    const int bid = blockIdx.x;
    const int tid = threadIdx.x;
    const int t = tid >> 6;
    const int c = tid & 63;
    int z = bid >> 6;
    int n2 = ((bid & 63) << 6) + c;

    const float2* src = D + ((size_t)z << 18) + n2;
    float2 g[8];
#pragma unroll
    for (int i = 0; i < 8; ++i)
        g[i] = src[(size_t)(8 * i + t) << 12];          // input[k1=8i+t]; 512B coalesced
    dft8<1>(g);
#pragma unroll
    for (int i = 1; i < 8; ++i)
        g[i] = cmulc(g[i], tab[64 * t * i]);            // W64^{+ti} = conj(tab[64 t i])
#pragma unroll
    for (int i = 0; i < 8; ++i) Lsh[(8 * t + i) * 64 + c] = g[i];   // phys x[8t+i]
    __syncthreads();
#pragma unroll
    for (int i = 0; i < 8; ++i) g[i] = Lsh[(t + 8 * i) * 64 + c];   // phys x[t+8i]
    dft8<1>(g);
    float* o0 = out + (size_t)(2 * z) * Lout;
    float* o1 = o0 + Lout;
#pragma unroll
    for (int i = 0; i < 8; ++i) {
        int n = ((t + 8 * i) << 12) + n2;               // n1 = t+8i natural
        if (n < Lout) { o0[n] = g[i].x; o1[n] = g[i].y; }
    }
}

extern "C" void kernel_launch(void* const* d_in, const int* in_sizes, int n_in,
                              void* d_out, int out_size, void* d_ws, size_t ws_size,
                              hipStream_t stream) {
    const float* audio = (const float*)d_in[0];   // (1, 4, T) f32
    const float* rir   = (const float*)d_in[1];   // (T,) f32
    float* out = (float*)d_out;                   // (1, 4, 2T-1) f32
    int Lout = out_size / 4;                      // 262143

    float2* A1  = (float2*)d_ws;                  // 3 * 2^18 complex (6.3 MB)
    float2* D   = A1 + 3 * NTOT;                  // 2 * 2^18 complex (4.2 MB)
    float2* tab = D + 2 * NTOT;                   // 4096 complex (32 KB)

    ka<<<192, 512, 0, stream>>>(audio, rir, A1, tab);
    kb<<<128, 512, 0, stream>>>(A1, D, tab);
    kc<<<128, 512, 0, stream>>>(D, out, Lout, tab);
}

// Round 13
// 24.834 us; speedup vs baseline: 1.0410x; 1.0410x over previous
//
#include <hip/hip_runtime.h>

// FFT convolution via N = 2^18 = 256 x 1024 Cooley-Tukey, 4 dispatches.
//   n = 1024*n1 + n2 (n1<256, nonzero n1<128), k = k1 + 256*k2.
// ka : distributed 256-pt column FFT over n1 (+ W_N^{-n2 k1}) -> A1[seq][k1][n2]
//      16 thr x 16 elems per column, ONE LDS exchange, in-register dft16.
// kbf: 768 blocks x 256: forward 1024-pt row FFT (radix-4 Stockham, 4 barriers)
//      -> Spec. 3 blocks/CU => barrier/latency stalls overlap across blocks.
// kbi: 512 blocks x 256: pointwise*1/N + inverse row FFT (+W_N^{+n2 k1}) -> D.
// kc : distributed 256-pt inverse column FFT over k1, unpack -> out.
// R6/R9/R10 lesson kept: no cross-block sync; dispatch boundary is the cheapest fence.

#define NTOT 262144
#define TLEN 131072
#define PI2_N    2.3968449808418217e-5f   /* 2*pi / 262144 */
#define PI2_1024 6.1359231515425649e-3f   /* 2*pi / 1024   */
#define PI2_256  2.4543692606170260e-2f   /* 2*pi / 256    */
#define LB(i) ((i) + ((i) >> 3))          /* LDS pad for row-FFT buffers */

__device__ __forceinline__ float2 cadd(float2 a, float2 b) { return make_float2(a.x + b.x, a.y + b.y); }
__device__ __forceinline__ float2 csub(float2 a, float2 b) { return make_float2(a.x - b.x, a.y - b.y); }
__device__ __forceinline__ float2 cmul(float2 a, float2 b) {
    return make_float2(a.x * b.x - a.y * b.y, a.x * b.y + a.y * b.x);
}
__device__ __forceinline__ float2 cmulc(float2 a, float2 b) {   // a * conj(b)
    return make_float2(a.x * b.x + a.y * b.y, a.y * b.x - a.x * b.y);
}
__device__ __forceinline__ float2 cexp_(float ang) {
    float s, c;
    __sincosf(ang, &s, &c);
    return make_float2(c, s);
}

// cos/sin(2*pi*k/16)
constexpr float CW16[16] = { 1.f, 0.92387953f, 0.70710678f, 0.38268343f, 0.f, -0.38268343f,
                             -0.70710678f, -0.92387953f, -1.f, -0.92387953f, -0.70710678f,
                             -0.38268343f, 0.f, 0.38268343f, 0.70710678f, 0.92387953f };
constexpr float SW16[16] = { 0.f, 0.38268343f, 0.70710678f, 0.92387953f, 1.f, 0.92387953f,
                             0.70710678f, 0.38268343f, 0.f, -0.38268343f, -0.70710678f,
                             -0.92387953f, -1.f, -0.92387953f, -0.70710678f, -0.38268343f };

template<int SIGN>
__device__ __forceinline__ void dft4(float2 x[4]) {
    float2 s0 = cadd(x[0], x[2]), d0 = csub(x[0], x[2]);
    float2 s1 = cadd(x[1], x[3]), d1 = csub(x[1], x[3]);
    float2 jd1 = (SIGN > 0) ? make_float2(-d1.y, d1.x) : make_float2(d1.y, -d1.x);
    x[0] = cadd(s0, s1);
    x[1] = cadd(d0, jd1);
    x[2] = csub(s0, s1);
    x[3] = csub(d0, jd1);
}

// Natural-order in-register 16-pt DFT (4x4). HZ: x[8..15] structurally zero (never read).
template<int SIGN, bool HZ>
__device__ __forceinline__ void dft16(float2 x[16]) {
    float2 A[4][4];                       // A[m0][j]
#pragma unroll
    for (int m0 = 0; m0 < 4; ++m0) {
        float2 g[4];
        if (HZ) {                         // dft4 of [a, b, 0, 0] over m1
            float2 a = x[m0], b = x[m0 + 4];
            float2 jb = (SIGN > 0) ? make_float2(-b.y, b.x) : make_float2(b.y, -b.x);
            g[0] = cadd(a, b);
            g[1] = cadd(a, jb);
            g[2] = csub(a, b);
            g[3] = csub(a, jb);
        } else {
            g[0] = x[m0]; g[1] = x[m0 + 4]; g[2] = x[m0 + 8]; g[3] = x[m0 + 12];
            dft4<SIGN>(g);
        }
#pragma unroll
        for (int j = 0; j < 4; ++j) {     // W16^{m0*j}, compile-time
            int k = (m0 * j) & 15;
            float2 w = make_float2(CW16[k], (SIGN < 0) ? -SW16[k] : SW16[k]);
            A[m0][j] = (m0 && j) ? cmul(g[j], w) : g[j];
        }
    }
#pragma unroll
    for (int j = 0; j < 4; ++j) {
        float2 g[4];
#pragma unroll
        for (int m0 = 0; m0 < 4; ++m0) g[m0] = A[m0][j];
        dft4<SIGN>(g);
#pragma unroll
        for (int l = 0; l < 4; ++l) x[j + 4 * l] = g[l];   // X[j+4l] natural
    }
}

template<int SIGN>
__device__ __forceinline__ void twtab4(float2 x[4], int base, const float2* __restrict__ tab) {
#pragma unroll
    for (int i = 1; i < 4; ++i) {
        float2 w = tab[base * i];          // base*i < 1024 at all call sites
        x[i] = (SIGN < 0) ? cmul(x[i], w) : cmulc(x[i], w);
    }
}

// 1024-pt radix-4 Stockham FFT, t in [0,256), x[i] = d[t+256i] natural in/out.
// 5 dft4 stages, 4 barriers, alternating L0/L1 (1152 float2 each).
template<int SIGN>
__device__ void fft1024(float2 x[4], int t, float2* L0, float2* L1,
                        const float2* __restrict__ tab) {
    dft4<SIGN>(x);
    twtab4<SIGN>(x, t, tab);
#pragma unroll
    for (int i = 0; i < 4; ++i) L0[LB(4 * t + i)] = x[i];
    __syncthreads();
    {
        int q = t & 3, p = t >> 2;
#pragma unroll
        for (int i = 0; i < 4; ++i) x[i] = L0[LB(q + 4 * p + 256 * i)];
        dft4<SIGN>(x);
        twtab4<SIGN>(x, 4 * p, tab);
#pragma unroll
        for (int i = 0; i < 4; ++i) L1[LB(q + 16 * p + 4 * i)] = x[i];
    }
    __syncthreads();
    {
        int q = t & 15, p = t >> 4;
#pragma unroll
        for (int i = 0; i < 4; ++i) x[i] = L1[LB(q + 16 * p + 256 * i)];
        dft4<SIGN>(x);
        twtab4<SIGN>(x, 16 * p, tab);
#pragma unroll
        for (int i = 0; i < 4; ++i) L0[LB(q + 64 * p + 16 * i)] = x[i];
    }
    __syncthreads();
    {
        int q = t & 63, p = t >> 6;
#pragma unroll
        for (int i = 0; i < 4; ++i) x[i] = L0[LB(q + 64 * p + 256 * i)];
        dft4<SIGN>(x);
        twtab4<SIGN>(x, 64 * p, tab);
#pragma unroll
        for (int i = 0; i < 4; ++i) L1[LB(q + 256 * p + 64 * i)] = x[i];
    }
    __syncthreads();
#pragma unroll
    for (int i = 0; i < 4; ++i) x[i] = L1[LB(t + 256 * i)];
    dft4<SIGN>(x);
}

// ka: 192 blocks x 256. 16 columns/block, 16 thr/column (c = tid&15 lane-consecutive).
// Column = 256-pt FFT over n1 (nonzero n1 < 128): in-reg dft16 (HZ) -> W256^{t a}
// -> LDS exchange -> in-reg dft16 -> W_N^{-n2 k1} -> A1[seq][k1][n2].
__global__ void __launch_bounds__(256) ka(const float* __restrict__ audio,
                                          const float* __restrict__ rir,
                                          float2* __restrict__ A1,
                                          float2* __restrict__ tab) {
    __shared__ float2 lds[256 * 17];      // [a*16+u][c] padded row stride 17
    const int bid = blockIdx.x;
    const int tid = threadIdx.x;
    const int c = tid & 15;
    const int t = tid >> 4;               // 0..15

    if (bid < 4)                          // fill W1024 table for kbf/kbi
        tab[bid * 256 + tid] = cexp_(-PI2_1024 * (float)(bid * 256 + tid));

    const int seq = bid >> 6;
    const int n2 = ((bid & 63) << 4) + c;

    float2 g[16];
    if (seq < 2) {
        const float* c0 = audio + (size_t)(2 * seq) * TLEN;
        const float* c1 = c0 + TLEN;
#pragma unroll
        for (int v = 0; v < 8; ++v) {     // n1 = t+16v < 128 nonzero half
            int n = ((t + 16 * v) << 10) + n2;
            g[v] = make_float2(c0[n], c1[n]);
        }
    } else {
#pragma unroll
        for (int v = 0; v < 8; ++v) {
            int n = ((t + 16 * v) << 10) + n2;
            g[v] = make_float2(rir[TLEN - 1 - n], 0.f);
        }
    }

    dft16<-1, true>(g);                   // bins a = reg index (natural)
#pragma unroll
    for (int r = 1; r < 16; ++r)          // W256^{-t*a}
        g[r] = cmul(g[r], cexp_(-PI2_256 * (float)(t * r)));
    if (t) g[0] = g[0];                   // no-op
#pragma unroll
    for (int r = 0; r < 16; ++r) lds[(r * 16 + t) * 17 + c] = g[r];
    __syncthreads();
#pragma unroll
    for (int u = 0; u < 16; ++u) g[u] = lds[(t * 16 + u) * 17 + c];  // a = t, sender u

    dft16<-1, false>(g);                  // over u -> bins b = reg index; k1 = t + 16b

    float2* dst = A1 + ((size_t)seq << 18) + n2;
#pragma unroll
    for (int r = 0; r < 16; ++r) {
        int k1 = t + 16 * r;
        float2 v = cmul(g[r], cexp_(-PI2_N * (float)(n2 * k1)));   // n2*k1 < 2^18 exact
        dst[(size_t)k1 << 10] = v;
    }
}

// kbf: 768 blocks x 256. One forward 1024-pt row FFT per (seq,k1) = bid.
__global__ void __launch_bounds__(256) kbf(const float2* __restrict__ A1,
                                           float2* __restrict__ Spec,
                                           const float2* __restrict__ tab) {
    __shared__ float2 L0[1152], L1[1152];
    const int t = threadIdx.x;
    const float2* src = A1 + ((size_t)blockIdx.x << 10);
    float2 x[4];
#pragma unroll
    for (int i = 0; i < 4; ++i) x[i] = src[t + 256 * i];
    fft1024<-1>(x, t, L0, L1, tab);
    float2* dst = Spec + ((size_t)blockIdx.x << 10) + t;
#pragma unroll
    for (int i = 0; i < 4; ++i) dst[256 * i] = x[i];
}

// kbi: 512 blocks x 256. z = bid>>8, k1 = bid&255. Pointwise*1/N + inverse FFT + twiddle.
__global__ void __launch_bounds__(256) kbi(const float2* __restrict__ Spec,
                                           float2* __restrict__ D,
                                           const float2* __restrict__ tab) {
    __shared__ float2 L0[1152], L1[1152];
    const int t = threadIdx.x;
    const int k1 = blockIdx.x & 255;

    const float2* sz = Spec + ((size_t)blockIdx.x << 10);        // z rows 0..511
    const float2* sr = Spec + ((size_t)(512 + k1) << 10);        // rir rows 512..767
    float2 x[4], r4[4];
#pragma unroll
    for (int i = 0; i < 4; ++i) x[i] = sz[t + 256 * i];
#pragma unroll
    for (int i = 0; i < 4; ++i) r4[i] = sr[t + 256 * i];

    const float invN = 3.814697265625e-6f;   // 1/262144
#pragma unroll
    for (int i = 0; i < 4; ++i) {
        float2 y = cmul(x[i], r4[i]);
        x[i] = make_float2(y.x * invN, y.y * invN);
    }

    fft1024<1>(x, t, L0, L1, tab);

    // W_N^{+n2 k1}, n2 = t+256i: w = e^{+i th (t k1)}, step = e^{+i 2pi k1/1024} = conj(tab[k1])
    float2 w  = cexp_(PI2_N * (float)(t * k1));
    float2 st = make_float2(tab[k1].x, -tab[k1].y);
    float2* d = D + ((size_t)blockIdx.x << 10) + t;
#pragma unroll
    for (int i = 0; i < 4; ++i) {
        d[256 * i] = cmul(x[i], w);
        w = cmul(w, st);
    }
}

// kc: 128 blocks x 256. Distributed 256-pt inverse column FFT over k1 + unpack.
__global__ void __launch_bounds__(256) kc(const float2* __restrict__ D,
                                          float* __restrict__ out, int Lout) {
    __shared__ float2 lds[256 * 17];
    const int bid = blockIdx.x;
    const int tid = threadIdx.x;
    const int c = tid & 15;
    const int t = tid >> 4;
    const int z = bid >> 6;
    const int n2 = ((bid & 63) << 4) + c;

    const float2* src = D + ((size_t)z << 18) + n2;
    float2 g[16];
#pragma unroll
    for (int v = 0; v < 16; ++v)
        g[v] = src[(size_t)(t + 16 * v) << 10];    // k1 = t+16v; 128B coalesced chunks

    dft16<1, false>(g);                            // bins a = reg index
#pragma unroll
    for (int r = 1; r < 16; ++r)                   // W256^{+t*a}
        g[r] = cmul(g[r], cexp_(PI2_256 * (float)(t * r)));
#pragma unroll
    for (int r = 0; r < 16; ++r) lds[(r * 16 + t) * 17 + c] = g[r];
    __syncthreads();
#pragma unroll
    for (int u = 0; u < 16; ++u) g[u] = lds[(t * 16 + u) * 17 + c];

    dft16<1, false>(g);                            // n1 = t + 16b

    float* o0 = out + (size_t)(2 * z) * Lout;
    float* o1 = o0 + Lout;
#pragma unroll
    for (int r = 0; r < 16; ++r) {
        int n = ((t + 16 * r) << 10) + n2;
        if (n < Lout) { o0[n] = g[r].x; o1[n] = g[r].y; }
    }
}

extern "C" void kernel_launch(void* const* d_in, const int* in_sizes, int n_in,
                              void* d_out, int out_size, void* d_ws, size_t ws_size,
                              hipStream_t stream) {
    const float* audio = (const float*)d_in[0];   // (1, 4, T) f32
    const float* rir   = (const float*)d_in[1];   // (T,) f32
    float* out = (float*)d_out;                   // (1, 4, 2T-1) f32
    int Lout = out_size / 4;                      // 262143

    float2* A1   = (float2*)d_ws;                 // 3 * 2^18 complex (6.3 MB)
    float2* Spec = A1 + 3 * NTOT;                 // 3 * 2^18 complex (6.3 MB)
    float2* D    = Spec + 3 * NTOT;               // 2 * 2^18 complex (4.2 MB)
    float2* tab  = D + 2 * NTOT;                  // 1024 complex (8 KB)

    ka <<<192, 256, 0, stream>>>(audio, rir, A1, tab);
    kbf<<<768, 256, 0, stream>>>(A1, Spec, tab);
    kbi<<<512, 256, 0, stream>>>(Spec, D, tab);
    kc <<<128, 256, 0, stream>>>(D, out, Lout);
}

// Round 14
// 22.622 us; speedup vs baseline: 1.1427x; 1.0978x over previous
//
#include <hip/hip_runtime.h>

// FFT convolution via N = 2^18 = 256 x 1024 Cooley-Tukey, 3 dispatches
// (minimum for four-step: col-pass | row-local middle | col-pass).
//   n = 1024*n1 + n2 (nonzero n1<128), k = k1 + 256*k2.
// ka: distributed 256-pt column FFT over n1 (+ W_N^{-n2 k1}) -> A1[seq][k1][n2]
//     16 thr x 16 elems per column, ONE LDS exchange, in-register dft16.
// kb: 512 blocks x 256 (2 blocks/CU): per (z,k1) row -- fwd 1024-FFT of rir row
//     (spectrum in 8 VGPRs; recomputed per z: cheaper than any cross-block
//     handshake per R6/R9/R10), fwd FFT of z row, pointwise*1/N, inverse FFT,
//     +W_N^{+n2 k1} -> D[z][k1][n2]. Loads issued before first FFT.
//     fft1024 chain calls are WAR-safe w/o extra barriers (dbuf parity).
// kc: distributed 256-pt inverse column FFT over k1, unpack -> out.

#define NTOT 262144
#define TLEN 131072
#define PI2_N    2.3968449808418217e-5f   /* 2*pi / 262144 */
#define PI2_1024 6.1359231515425649e-3f   /* 2*pi / 1024   */
#define PI2_256  2.4543692606170260e-2f   /* 2*pi / 256    */
#define LB(i) ((i) + ((i) >> 3))          /* LDS pad for row-FFT buffers */

__device__ __forceinline__ float2 cadd(float2 a, float2 b) { return make_float2(a.x + b.x, a.y + b.y); }
__device__ __forceinline__ float2 csub(float2 a, float2 b) { return make_float2(a.x - b.x, a.y - b.y); }
__device__ __forceinline__ float2 cmul(float2 a, float2 b) {
    return make_float2(a.x * b.x - a.y * b.y, a.x * b.y + a.y * b.x);
}
__device__ __forceinline__ float2 cmulc(float2 a, float2 b) {   // a * conj(b)
    return make_float2(a.x * b.x + a.y * b.y, a.y * b.x - a.x * b.y);
}
__device__ __forceinline__ float2 cexp_(float ang) {
    float s, c;
    __sincosf(ang, &s, &c);
    return make_float2(c, s);
}

// cos/sin(2*pi*k/16)
constexpr float CW16[16] = { 1.f, 0.92387953f, 0.70710678f, 0.38268343f, 0.f, -0.38268343f,
                             -0.70710678f, -0.92387953f, -1.f, -0.92387953f, -0.70710678f,
                             -0.38268343f, 0.f, 0.38268343f, 0.70710678f, 0.92387953f };
constexpr float SW16[16] = { 0.f, 0.38268343f, 0.70710678f, 0.92387953f, 1.f, 0.92387953f,
                             0.70710678f, 0.38268343f, 0.f, -0.38268343f, -0.70710678f,
                             -0.92387953f, -1.f, -0.92387953f, -0.70710678f, -0.38268343f };

template<int SIGN>
__device__ __forceinline__ void dft4(float2 x[4]) {
    float2 s0 = cadd(x[0], x[2]), d0 = csub(x[0], x[2]);
    float2 s1 = cadd(x[1], x[3]), d1 = csub(x[1], x[3]);
    float2 jd1 = (SIGN > 0) ? make_float2(-d1.y, d1.x) : make_float2(d1.y, -d1.x);
    x[0] = cadd(s0, s1);
    x[1] = cadd(d0, jd1);
    x[2] = csub(s0, s1);
    x[3] = csub(d0, jd1);
}

// Natural-order in-register 16-pt DFT (4x4). HZ: x[8..15] structurally zero (never read).
template<int SIGN, bool HZ>
__device__ __forceinline__ void dft16(float2 x[16]) {
    float2 A[4][4];                       // A[m0][j]
#pragma unroll
    for (int m0 = 0; m0 < 4; ++m0) {
        float2 g[4];
        if (HZ) {                         // dft4 of [a, b, 0, 0] over m1
            float2 a = x[m0], b = x[m0 + 4];
            float2 jb = (SIGN > 0) ? make_float2(-b.y, b.x) : make_float2(b.y, -b.x);
            g[0] = cadd(a, b);
            g[1] = cadd(a, jb);
            g[2] = csub(a, b);
            g[3] = csub(a, jb);
        } else {
            g[0] = x[m0]; g[1] = x[m0 + 4]; g[2] = x[m0 + 8]; g[3] = x[m0 + 12];
            dft4<SIGN>(g);
        }
#pragma unroll
        for (int j = 0; j < 4; ++j) {     // W16^{m0*j}, compile-time
            int k = (m0 * j) & 15;
            float2 w = make_float2(CW16[k], (SIGN < 0) ? -SW16[k] : SW16[k]);
            A[m0][j] = (m0 && j) ? cmul(g[j], w) : g[j];
        }
    }
#pragma unroll
    for (int j = 0; j < 4; ++j) {
        float2 g[4];
#pragma unroll
        for (int m0 = 0; m0 < 4; ++m0) g[m0] = A[m0][j];
        dft4<SIGN>(g);
#pragma unroll
        for (int l = 0; l < 4; ++l) x[j + 4 * l] = g[l];   // X[j+4l] natural
    }
}

template<int SIGN>
__device__ __forceinline__ void twtab4(float2 x[4], int base, const float2* __restrict__ tab) {
#pragma unroll
    for (int i = 1; i < 4; ++i) {
        float2 w = tab[base * i];          // base*i < 1024 at all call sites
        x[i] = (SIGN < 0) ? cmul(x[i], w) : cmulc(x[i], w);
    }
}

// 1024-pt radix-4 Stockham FFT, t in [0,256), x[i] = d[t+256i] natural in/out.
// 5 dft4 stages, 4 barriers, alternating L0/L1. Back-to-back calls WAR-safe.
template<int SIGN>
__device__ void fft1024(float2 x[4], int t, float2* L0, float2* L1,
                        const float2* __restrict__ tab) {
    dft4<SIGN>(x);
    twtab4<SIGN>(x, t, tab);
#pragma unroll
    for (int i = 0; i < 4; ++i) L0[LB(4 * t + i)] = x[i];
    __syncthreads();
    {
        int q = t & 3, p = t >> 2;
#pragma unroll
        for (int i = 0; i < 4; ++i) x[i] = L0[LB(q + 4 * p + 256 * i)];
        dft4<SIGN>(x);
        twtab4<SIGN>(x, 4 * p, tab);
#pragma unroll
        for (int i = 0; i < 4; ++i) L1[LB(q + 16 * p + 4 * i)] = x[i];
    }
    __syncthreads();
    {
        int q = t & 15, p = t >> 4;
#pragma unroll
        for (int i = 0; i < 4; ++i) x[i] = L1[LB(q + 16 * p + 256 * i)];
        dft4<SIGN>(x);
        twtab4<SIGN>(x, 16 * p, tab);
#pragma unroll
        for (int i = 0; i < 4; ++i) L0[LB(q + 64 * p + 16 * i)] = x[i];
    }
    __syncthreads();
    {
        int q = t & 63, p = t >> 6;
#pragma unroll
        for (int i = 0; i < 4; ++i) x[i] = L0[LB(q + 64 * p + 256 * i)];
        dft4<SIGN>(x);
        twtab4<SIGN>(x, 64 * p, tab);
#pragma unroll
        for (int i = 0; i < 4; ++i) L1[LB(q + 256 * p + 64 * i)] = x[i];
    }
    __syncthreads();
#pragma unroll
    for (int i = 0; i < 4; ++i) x[i] = L1[LB(t + 256 * i)];
    dft4<SIGN>(x);
}

// ka: 192 blocks x 256. 16 columns/block, 16 thr/column (c = tid&15 lane-consecutive).
__global__ void __launch_bounds__(256) ka(const float* __restrict__ audio,
                                          const float* __restrict__ rir,
                                          float2* __restrict__ A1,
                                          float2* __restrict__ tab) {
    __shared__ float2 lds[256 * 17];      // [a*16+u][c] padded row stride 17
    const int bid = blockIdx.x;
    const int tid = threadIdx.x;
    const int c = tid & 15;
    const int t = tid >> 4;               // 0..15

    if (bid < 4)                          // fill W1024 table for kb
        tab[bid * 256 + tid] = cexp_(-PI2_1024 * (float)(bid * 256 + tid));

    const int seq = bid >> 6;
    const int n2 = ((bid & 63) << 4) + c;

    float2 g[16];
    if (seq < 2) {
        const float* c0 = audio + (size_t)(2 * seq) * TLEN;
        const float* c1 = c0 + TLEN;
#pragma unroll
        for (int v = 0; v < 8; ++v) {     // n1 = t+16v < 128 nonzero half
            int n = ((t + 16 * v) << 10) + n2;
            g[v] = make_float2(c0[n], c1[n]);
        }
    } else {
#pragma unroll
        for (int v = 0; v < 8; ++v) {
            int n = ((t + 16 * v) << 10) + n2;
            g[v] = make_float2(rir[TLEN - 1 - n], 0.f);
        }
    }

    dft16<-1, true>(g);                   // bins a = reg index (natural)
#pragma unroll
    for (int r = 1; r < 16; ++r)          // W256^{-t*a}
        g[r] = cmul(g[r], cexp_(-PI2_256 * (float)(t * r)));
#pragma unroll
    for (int r = 0; r < 16; ++r) lds[(r * 16 + t) * 17 + c] = g[r];
    __syncthreads();
#pragma unroll
    for (int u = 0; u < 16; ++u) g[u] = lds[(t * 16 + u) * 17 + c];  // a = t, sender u

    dft16<-1, false>(g);                  // over u -> bins b = reg index; k1 = t + 16b

    float2* dst = A1 + ((size_t)seq << 18) + n2;
#pragma unroll
    for (int r = 0; r < 16; ++r) {
        int k1 = t + 16 * r;
        float2 v = cmul(g[r], cexp_(-PI2_N * (float)(n2 * k1)));   // n2*k1 < 2^18 exact
        dst[(size_t)k1 << 10] = v;
    }
}

// kb: 512 blocks x 256. z = bid>>8, k1 = bid&255. Row-local middle:
// fwd FFT(rir row) -> 8 VGPRs; fwd FFT(z row); pointwise*1/N; inv FFT; twiddle -> D.
__global__ void __launch_bounds__(256) kb(const float2* __restrict__ A1,
                                          float2* __restrict__ D,
                                          const float2* __restrict__ tab) {
    __shared__ float2 L0[1152], L1[1152];
    const int t = threadIdx.x;
    const int k1 = blockIdx.x & 255;

    const float2* sz = A1 + ((size_t)blockIdx.x << 10);          // z row = z*256+k1 = bid
    const float2* sr = A1 + ((size_t)(512 + k1) << 10);          // rir row
    float2 x[4], r4[4];
#pragma unroll
    for (int i = 0; i < 4; ++i) x[i] = sz[t + 256 * i];          // issue early: both
#pragma unroll
    for (int i = 0; i < 4; ++i) r4[i] = sr[t + 256 * i];         // rows in flight

    fft1024<-1>(r4, t, L0, L1, tab);     // rir spectrum (z loads hide under this)
    fft1024<-1>(x, t, L0, L1, tab);      // z spectrum

    const float invN = 3.814697265625e-6f;   // 1/262144
#pragma unroll
    for (int i = 0; i < 4; ++i) {
        float2 y = cmul(x[i], r4[i]);
        x[i] = make_float2(y.x * invN, y.y * invN);
    }

    fft1024<1>(x, t, L0, L1, tab);

    // W_N^{+n2 k1}, n2 = t+256i: w = e^{+i th(t k1)}, step = conj(tab[k1]) = e^{+2pi i k1/1024}
    float2 w  = cexp_(PI2_N * (float)(t * k1));
    float2 st = make_float2(tab[k1].x, -tab[k1].y);
    float2* d = D + ((size_t)blockIdx.x << 10) + t;
#pragma unroll
    for (int i = 0; i < 4; ++i) {
        d[256 * i] = cmul(x[i], w);
        w = cmul(w, st);
    }
}

// kc: 128 blocks x 256. Distributed 256-pt inverse column FFT over k1 + unpack.
__global__ void __launch_bounds__(256) kc(const float2* __restrict__ D,
                                          float* __restrict__ out, int Lout) {
    __shared__ float2 lds[256 * 17];
    const int bid = blockIdx.x;
    const int tid = threadIdx.x;
    const int c = tid & 15;
    const int t = tid >> 4;
    const int z = bid >> 6;
    const int n2 = ((bid & 63) << 4) + c;

    const float2* src = D + ((size_t)z << 18) + n2;
    float2 g[16];
#pragma unroll
    for (int v = 0; v < 16; ++v)
        g[v] = src[(size_t)(t + 16 * v) << 10];    // k1 = t+16v; 128B coalesced chunks

    dft16<1, false>(g);                            // bins a = reg index
#pragma unroll
    for (int r = 1; r < 16; ++r)                   // W256^{+t*a}
        g[r] = cmul(g[r], cexp_(PI2_256 * (float)(t * r)));
#pragma unroll
    for (int r = 0; r < 16; ++r) lds[(r * 16 + t) * 17 + c] = g[r];
    __syncthreads();
#pragma unroll
    for (int u = 0; u < 16; ++u) g[u] = lds[(t * 16 + u) * 17 + c];

    dft16<1, false>(g);                            // n1 = t + 16b

    float* o0 = out + (size_t)(2 * z) * Lout;
    float* o1 = o0 + Lout;
#pragma unroll
    for (int r = 0; r < 16; ++r) {
        int n = ((t + 16 * r) << 10) + n2;
        if (n < Lout) { o0[n] = g[r].x; o1[n] = g[r].y; }
    }
}

extern "C" void kernel_launch(void* const* d_in, const int* in_sizes, int n_in,
                              void* d_out, int out_size, void* d_ws, size_t ws_size,
                              hipStream_t stream) {
    const float* audio = (const float*)d_in[0];   // (1, 4, T) f32
    const float* rir   = (const float*)d_in[1];   // (T,) f32
    float* out = (float*)d_out;                   // (1, 4, 2T-1) f32
    int Lout = out_size / 4;                      // 262143

    float2* A1  = (float2*)d_ws;                  // 3 * 2^18 complex (6.3 MB)
    float2* D   = A1 + 3 * NTOT;                  // 2 * 2^18 complex (4.2 MB)
    float2* tab = D + 2 * NTOT;                   // 1024 complex (8 KB)

    ka<<<192, 256, 0, stream>>>(audio, rir, A1, tab);
    kb<<<512, 256, 0, stream>>>(A1, D, tab);
    kc<<<128, 256, 0, stream>>>(D, out, Lout);
}